// Round 3
// baseline (438.819 us; speedup 1.0000x reference)
//
#include <hip/hip_runtime.h>

// MultiHeadAttention: B=2, S=2048, D=1024, H=16, HD=64, scores MULTIPLIED by 64.
// Pipeline: proj (split-fp16 3-term MFMA GEMM) -> vh transpose -> flash attention.
// Flash v3: ZERO LDS, zero barriers. K/V fragments load directly from global
// (layouts are fragment-contiguous); P stays in registers via a key-permutation
// key(k=quad*8+j, kc) = 32kc + 16(j>>2) + 4*quad + (j&3) applied consistently to
// the PV A-operand (V columns) and B-operand (own sacc values). 32 q per wave,
// 1-wave blocks, grid (bh=32, qb=64): linear%8 XCD round-robin pins each bh's
// K/V (768 KB) to one XCD L2.
// Workspace layout (needs 48 MB): qh_hi, qh_lo, kh_hi, kh_lo, vh, vhT (8 MB each)

typedef _Float16 half4 __attribute__((ext_vector_type(4)));
typedef _Float16 half8 __attribute__((ext_vector_type(8)));
typedef float floatx4 __attribute__((ext_vector_type(4)));

#define MFMA_F16(a, b, c) __builtin_amdgcn_mfma_f32_16x16x32_f16((a), (b), (c), 0, 0, 0)

constexpr int SEQ = 2048;
constexpr int DM = 1024;
constexpr int NH = 16;
constexpr int HD = 64;
// 64 * log2(e): fold score scale + base-2 conversion into Q projection
constexpr float QSCALE = 92.33248261689366f;

__device__ inline void split4(const float4 f, half4& h, half4& l) {
  h[0] = (_Float16)f.x; l[0] = (_Float16)(f.x - (float)h[0]);
  h[1] = (_Float16)f.y; l[1] = (_Float16)(f.y - (float)h[1]);
  h[2] = (_Float16)f.z; l[2] = (_Float16)(f.z - (float)h[2]);
  h[3] = (_Float16)f.w; l[3] = (_Float16)(f.w - (float)h[3]);
}

// ---------------- projection GEMM: y = x @ W^T ----------------
__global__ __launch_bounds__(256) void proj_kernel(
    const float* __restrict__ q, const float* __restrict__ k, const float* __restrict__ v,
    const float* __restrict__ Wq, const float* __restrict__ Wk, const float* __restrict__ Wv,
    _Float16* __restrict__ qh_hi, _Float16* __restrict__ qh_lo,
    _Float16* __restrict__ kh_hi, _Float16* __restrict__ kh_lo,
    _Float16* __restrict__ vh)
{
  const int z = blockIdx.z;
  const float* __restrict__ x = (z == 0) ? q : (z == 1) ? k : v;
  const float* __restrict__ W = (z == 0) ? Wq : (z == 1) ? Wk : Wv;

  __shared__ __align__(16) _Float16 As[2][128][40];  // [hi/lo][m][k], pad 32->40
  __shared__ __align__(16) _Float16 Bs[2][128][40];  // [hi/lo][n][k]

  const int tid = threadIdx.x;
  const int bm = blockIdx.x;          // 0..31  (M=4096 / 128)
  const int bn = blockIdx.y;          // 0..7   (N=1024 / 128)
  const int lane = tid & 63;
  const int l15 = lane & 15;
  const int quad = lane >> 4;
  const int w = tid >> 6;
  const int wm = w >> 1;
  const int wn = w & 1;

  floatx4 acc[4][4];
  #pragma unroll
  for (int mt = 0; mt < 4; mt++)
    #pragma unroll
    for (int nt = 0; nt < 4; nt++)
      acc[mt][nt] = (floatx4){0.f, 0.f, 0.f, 0.f};

  for (int kk = 0; kk < DM; kk += 32) {
    __syncthreads();
    #pragma unroll
    for (int i = 0; i < 4; i++) {
      int c = i * 256 + tid;
      int row = c >> 3;
      int col = (c & 7) * 4;
      float4 fa = *(const float4*)(x + (size_t)(bm * 128 + row) * DM + kk + col);
      float4 fb = *(const float4*)(W + (size_t)(bn * 128 + row) * DM + kk + col);
      half4 ah, al, bh_, bl_;
      split4(fa, ah, al);
      split4(fb, bh_, bl_);
      *(half4*)&As[0][row][col] = ah;
      *(half4*)&As[1][row][col] = al;
      *(half4*)&Bs[0][row][col] = bh_;
      *(half4*)&Bs[1][row][col] = bl_;
    }
    __syncthreads();

    half8 a_h[4], a_l[4], b_h[4], b_l[4];
    #pragma unroll
    for (int t = 0; t < 4; t++) {
      a_h[t] = *(const half8*)&As[0][wm * 64 + t * 16 + l15][quad * 8];
      a_l[t] = *(const half8*)&As[1][wm * 64 + t * 16 + l15][quad * 8];
      b_h[t] = *(const half8*)&Bs[0][wn * 64 + t * 16 + l15][quad * 8];
      b_l[t] = *(const half8*)&Bs[1][wn * 64 + t * 16 + l15][quad * 8];
    }
    if (z == 2) {
      #pragma unroll
      for (int mt = 0; mt < 4; mt++)
        #pragma unroll
        for (int nt = 0; nt < 4; nt++)
          acc[mt][nt] = MFMA_F16(a_h[mt], b_h[nt], acc[mt][nt]);
    } else {
      #pragma unroll
      for (int mt = 0; mt < 4; mt++)
        #pragma unroll
        for (int nt = 0; nt < 4; nt++) {
          floatx4 t0 = MFMA_F16(a_h[mt], b_h[nt], acc[mt][nt]);
          t0 = MFMA_F16(a_h[mt], b_l[nt], t0);
          acc[mt][nt] = MFMA_F16(a_l[mt], b_h[nt], t0);
        }
    }
  }

  const float scale = (z == 0) ? QSCALE : 1.0f;
  #pragma unroll
  for (int mt = 0; mt < 4; mt++)
    #pragma unroll
    for (int nt = 0; nt < 4; nt++)
      #pragma unroll
      for (int r = 0; r < 4; r++) {
        int gm = bm * 128 + wm * 64 + mt * 16 + quad * 4 + r;   // (b,s)
        int gn = bn * 128 + wn * 64 + nt * 16 + l15;            // h*64+hd
        int b = gm >> 11, s = gm & 2047;
        int h = gn >> 6, hd = gn & 63;
        size_t idx = ((size_t)(b * NH + h) * SEQ + s) * HD + hd;
        float val = acc[mt][nt][r] * scale;
        if (z == 2) {
          vh[idx] = (_Float16)val;
        } else {
          _Float16 hi = (_Float16)val;
          _Float16 lo = (_Float16)(val - (float)hi);
          if (z == 0) { qh_hi[idx] = hi; qh_lo[idx] = lo; }
          else        { kh_hi[idx] = hi; kh_lo[idx] = lo; }
        }
      }
}

// ---------------- vh [b,h,s,64] -> vhT [b,h,64,s] ----------------
__global__ __launch_bounds__(256) void transpose_v(const _Float16* __restrict__ vh,
                                                   _Float16* __restrict__ vhT)
{
  __shared__ __align__(16) _Float16 T[128][72];
  const int bh = blockIdx.x;
  const int sc = blockIdx.y;
  const int tid = threadIdx.x;
  const _Float16* src = vh + ((size_t)bh * SEQ + sc * 128) * HD;
  #pragma unroll
  for (int i = 0; i < 4; i++) {
    int c = i * 256 + tid;
    int row = c >> 3, off = (c & 7) * 8;
    *(half8*)&T[row][off] = *(const half8*)(src + (size_t)row * HD + off);
  }
  __syncthreads();
  _Float16* dst = vhT + (size_t)bh * HD * SEQ + sc * 128;
  #pragma unroll
  for (int i = 0; i < 4; i++) {
    int c = i * 256 + tid;
    int hd = c >> 4, off = (c & 15) * 8;
    half8 vv;
    #pragma unroll
    for (int j = 0; j < 8; j++) vv[j] = T[off + j][hd];
    *(half8*)(dst + (size_t)hd * SEQ + off) = vv;
  }
}

// ---------------- flash attention v3 (zero LDS, register-resident P) --------
// 1 wave per block, 32 q per wave (two 16-q groups sharing K/V fragments).
// S^T = K·Q^T  (C: row=key-in-16=quad*4+r, col=q=l15)
// O^T = V~·P~  with permuted key order; P stays in registers.
__global__ __launch_bounds__(64, 2) void flash_kernel(
    const _Float16* __restrict__ qh_hi, const _Float16* __restrict__ qh_lo,
    const _Float16* __restrict__ kh_hi, const _Float16* __restrict__ kh_lo,
    const _Float16* __restrict__ vhT, float* __restrict__ out)
{
  const int bh = blockIdx.x;          // 0..31
  const int qb = blockIdx.y;          // 0..63 (32 q-rows per block)
  const int lane = threadIdx.x;       // 0..63
  const int l15 = lane & 15;
  const int quad = lane >> 4;

  const size_t bh_off = (size_t)bh * SEQ * HD;
  const _Float16* __restrict__ kh_p = kh_hi + bh_off;
  const _Float16* __restrict__ kl_p = kh_lo + bh_off;
  const _Float16* __restrict__ vt_p = vhT + (size_t)bh * HD * SEQ;
  const int qrow0 = qb * 32;

  // Q as B-operand fragments: lane holds n=q=l15, k=d=kc*32+quad*8+j
  half8 bqh[2][2], bql[2][2];         // [g][kc]
  #pragma unroll
  for (int g = 0; g < 2; g++) {
    const _Float16* qp_h = qh_hi + bh_off + (size_t)(qrow0 + g * 16 + l15) * HD;
    const _Float16* qp_l = qh_lo + bh_off + (size_t)(qrow0 + g * 16 + l15) * HD;
    #pragma unroll
    for (int kc = 0; kc < 2; kc++) {
      bqh[g][kc] = *(const half8*)(qp_h + kc * 32 + quad * 8);
      bql[g][kc] = *(const half8*)(qp_l + kc * 32 + quad * 8);
    }
  }

  float m_[2] = {-3.0e38f, -3.0e38f};
  float l_[2] = {0.f, 0.f};
  floatx4 Oacc[2][4];
  #pragma unroll
  for (int g = 0; g < 2; g++)
    #pragma unroll
    for (int nd = 0; nd < 4; nd++) Oacc[g][nd] = (floatx4){0.f, 0.f, 0.f, 0.f};

  for (int kt = 0; kt < SEQ / 64; kt++) {
    const int kbase = kt * 64;

    // K A-fragments direct from global: rows kbase+16nt+l15, cols kc*32+quad*8
    half8 akh[4][2], akl[4][2];
    #pragma unroll
    for (int nt = 0; nt < 4; nt++) {
      const _Float16* krh = kh_p + (size_t)(kbase + 16 * nt + l15) * HD + quad * 8;
      const _Float16* krl = kl_p + (size_t)(kbase + 16 * nt + l15) * HD + quad * 8;
      #pragma unroll
      for (int kc = 0; kc < 2; kc++) {
        akh[nt][kc] = *(const half8*)(krh + kc * 32);
        akl[nt][kc] = *(const half8*)(krl + kc * 32);
      }
    }
    // V A-fragments with permuted key order: element j of (nd,kc) is
    // vhT[nd*16+l15][kbase + 32kc + 16*(j>>2) + 4*quad + (j&3)]
    half8 av[4][2];
    #pragma unroll
    for (int nd = 0; nd < 4; nd++) {
      const _Float16* vr = vt_p + (size_t)(nd * 16 + l15) * SEQ + kbase + quad * 4;
      #pragma unroll
      for (int kc = 0; kc < 2; kc++) {
        half4 lo = *(const half4*)(vr + kc * 32);
        half4 hi = *(const half4*)(vr + kc * 32 + 16);
        #pragma unroll
        for (int j = 0; j < 4; j++) { av[nd][kc][j] = lo[j]; av[nd][kc][j + 4] = hi[j]; }
      }
    }

    #pragma unroll
    for (int g = 0; g < 2; g++) {
      // S^T tile: sacc[nt][r] = S[key=16nt+4quad+r][q=l15] (3-term split fp16)
      floatx4 sacc[4];
      #pragma unroll
      for (int nt = 0; nt < 4; nt++) {
        floatx4 s4 = (floatx4){0.f, 0.f, 0.f, 0.f};
        s4 = MFMA_F16(akh[nt][0], bqh[g][0], s4);
        s4 = MFMA_F16(akh[nt][1], bqh[g][1], s4);
        s4 = MFMA_F16(akh[nt][0], bql[g][0], s4);
        s4 = MFMA_F16(akh[nt][1], bql[g][1], s4);
        s4 = MFMA_F16(akl[nt][0], bqh[g][0], s4);
        s4 = MFMA_F16(akl[nt][1], bqh[g][1], s4);
        sacc[nt] = s4;
      }

      // online softmax over 64 keys: 15 in-lane max + 2 cross-quad shuffles
      float rmax = sacc[0][0];
      #pragma unroll
      for (int nt = 0; nt < 4; nt++)
        #pragma unroll
        for (int r = 0; r < 4; r++) rmax = fmaxf(rmax, sacc[nt][r]);
      rmax = fmaxf(rmax, __shfl_xor(rmax, 16, 64));
      rmax = fmaxf(rmax, __shfl_xor(rmax, 32, 64));
      const float mnew = fmaxf(m_[g], rmax);
      const float alpha = exp2f(m_[g] - mnew);
      m_[g] = mnew;

      float p[4][4];
      float rsum = 0.f;
      #pragma unroll
      for (int nt = 0; nt < 4; nt++)
        #pragma unroll
        for (int r = 0; r < 4; r++) {
          p[nt][r] = exp2f(sacc[nt][r] - mnew);
          rsum += p[nt][r];
        }
      rsum += __shfl_xor(rsum, 16, 64);
      rsum += __shfl_xor(rsum, 32, 64);
      l_[g] = l_[g] * alpha + rsum;

      // pack P for PV B-operand: bp8[kc][j] = p[2kc + (j>>2)][j&3]  (all in-lane)
      half8 bp8[2];
      #pragma unroll
      for (int kc = 0; kc < 2; kc++)
        #pragma unroll
        for (int j = 0; j < 8; j++)
          bp8[kc][j] = (_Float16)p[2 * kc + (j >> 2)][j & 3];

      #pragma unroll
      for (int nd = 0; nd < 4; nd++) {
        Oacc[g][nd][0] *= alpha; Oacc[g][nd][1] *= alpha;
        Oacc[g][nd][2] *= alpha; Oacc[g][nd][3] *= alpha;
        Oacc[g][nd] = MFMA_F16(av[nd][0], bp8[0], Oacc[g][nd]);
        Oacc[g][nd] = MFMA_F16(av[nd][1], bp8[1], Oacc[g][nd]);
      }
    }
  }

  // epilogue: O^T C-layout (row=d=nd*16+quad*4+r, col=q=l15) -> out fp32
  const int b = bh >> 4, h = bh & 15;
  #pragma unroll
  for (int g = 0; g < 2; g++) {
    const int s = qrow0 + g * 16 + l15;
    const float rinv = 1.0f / l_[g];
    float* obase = out + (size_t)(b * SEQ + s) * DM + h * HD;
    #pragma unroll
    for (int nd = 0; nd < 4; nd++) {
      float4 vv;
      vv.x = Oacc[g][nd][0] * rinv;
      vv.y = Oacc[g][nd][1] * rinv;
      vv.z = Oacc[g][nd][2] * rinv;
      vv.w = Oacc[g][nd][3] * rinv;
      *(float4*)(obase + nd * 16 + quad * 4) = vv;
    }
  }
}

extern "C" void kernel_launch(void* const* d_in, const int* in_sizes, int n_in,
                              void* d_out, int out_size, void* d_ws, size_t ws_size,
                              hipStream_t stream) {
  const float* q  = (const float*)d_in[0];
  const float* k  = (const float*)d_in[1];
  const float* v  = (const float*)d_in[2];
  const float* Wq = (const float*)d_in[3];
  const float* Wk = (const float*)d_in[4];
  const float* Wv = (const float*)d_in[5];
  float* out = (float*)d_out;

  const size_t SZ = (size_t)2 * NH * SEQ * HD;  // 8 MB per array
  _Float16* ws    = (_Float16*)d_ws;            // 48 MB total
  _Float16* qh_hi = ws + 0 * SZ;
  _Float16* qh_lo = ws + 1 * SZ;
  _Float16* kh_hi = ws + 2 * SZ;
  _Float16* kh_lo = ws + 3 * SZ;
  _Float16* vh    = ws + 4 * SZ;
  _Float16* vhT   = ws + 5 * SZ;

  proj_kernel<<<dim3(32, 8, 3), 256, 0, stream>>>(q, k, v, Wq, Wk, Wv,
                                                  qh_hi, qh_lo, kh_hi, kh_lo, vh);
  transpose_v<<<dim3(32, 16), 256, 0, stream>>>(vh, vhT);
  flash_kernel<<<dim3(32, 64), 64, 0, stream>>>(qh_hi, qh_lo, kh_hi, kh_lo, vhT, out);
}

// Round 4
// 381.858 us; speedup vs baseline: 1.1492x; 1.1492x over previous
//
#include <hip/hip_runtime.h>

// MultiHeadAttention: B=2, S=2048, D=1024, H=16, HD=64, scores MULTIPLIED by 64.
// Pipeline: proj (split-fp16 3-term MFMA GEMM; z=2 writes permuted V^T directly)
//        -> flash attention (LDS-staged K/V, register-resident P, 32 q/wave).
// Key-permutation trick: PV contracts keys in order key = 32kc+16(j>>2)+4quad+(j&3);
// B-operand = lane's own softmax values (P never leaves registers); V^T columns are
// pre-permuted in global so A-fragments are contiguous b128 LDS reads.
// Workspace (40 MB): qh_hi, qh_lo, kh_hi, kh_lo, vhT_perm (8 MB each)

typedef _Float16 half4 __attribute__((ext_vector_type(4)));
typedef _Float16 half8 __attribute__((ext_vector_type(8)));
typedef float floatx4 __attribute__((ext_vector_type(4)));

#define MFMA_F16(a, b, c) __builtin_amdgcn_mfma_f32_16x16x32_f16((a), (b), (c), 0, 0, 0)

constexpr int SEQ = 2048;
constexpr int DM = 1024;
constexpr int NH = 16;
constexpr int HD = 64;
// 64 * log2(e): fold score scale + base-2 conversion into Q projection
constexpr float QSCALE = 92.33248261689366f;

__device__ inline void split4(const float4 f, half4& h, half4& l) {
  h[0] = (_Float16)f.x; l[0] = (_Float16)(f.x - (float)h[0]);
  h[1] = (_Float16)f.y; l[1] = (_Float16)(f.y - (float)h[1]);
  h[2] = (_Float16)f.z; l[2] = (_Float16)(f.z - (float)h[2]);
  h[3] = (_Float16)f.w; l[3] = (_Float16)(f.w - (float)h[3]);
}

// ---------------- projection GEMM: y = x @ W^T ----------------
// z=0: Q (scaled, hi/lo out)  z=1: K (hi/lo out)  z=2: V (fp16, permuted V^T out)
__global__ __launch_bounds__(256) void proj_kernel(
    const float* __restrict__ q, const float* __restrict__ k, const float* __restrict__ v,
    const float* __restrict__ Wq, const float* __restrict__ Wk, const float* __restrict__ Wv,
    _Float16* __restrict__ qh_hi, _Float16* __restrict__ qh_lo,
    _Float16* __restrict__ kh_hi, _Float16* __restrict__ kh_lo,
    _Float16* __restrict__ vhT)
{
  const int z = blockIdx.z;
  const float* __restrict__ x = (z == 0) ? q : (z == 1) ? k : v;
  const float* __restrict__ W = (z == 0) ? Wq : (z == 1) ? Wk : Wv;

  __shared__ __align__(16) _Float16 As[2][128][40];  // [hi/lo][m][k], pad 32->40
  __shared__ __align__(16) _Float16 Bs[2][128][40];  // [hi/lo][n][k]

  const int tid = threadIdx.x;
  const int bm = blockIdx.x;          // 0..31  (M=4096 / 128)
  const int bn = blockIdx.y;          // 0..7   (N=1024 / 128)
  const int lane = tid & 63;
  const int l15 = lane & 15;
  const int quad = lane >> 4;
  const int w = tid >> 6;
  const int wm = w >> 1;
  const int wn = w & 1;

  floatx4 acc[4][4];
  #pragma unroll
  for (int mt = 0; mt < 4; mt++)
    #pragma unroll
    for (int nt = 0; nt < 4; nt++)
      acc[mt][nt] = (floatx4){0.f, 0.f, 0.f, 0.f};

  for (int kk = 0; kk < DM; kk += 32) {
    __syncthreads();
    #pragma unroll
    for (int i = 0; i < 4; i++) {
      int c = i * 256 + tid;
      int row = c >> 3;
      int col = (c & 7) * 4;
      float4 fa = *(const float4*)(x + (size_t)(bm * 128 + row) * DM + kk + col);
      float4 fb = *(const float4*)(W + (size_t)(bn * 128 + row) * DM + kk + col);
      half4 ah, al, bh_, bl_;
      if (z == 2) {
        ah[0] = (_Float16)fa.x; ah[1] = (_Float16)fa.y;
        ah[2] = (_Float16)fa.z; ah[3] = (_Float16)fa.w;
        bh_[0] = (_Float16)fb.x; bh_[1] = (_Float16)fb.y;
        bh_[2] = (_Float16)fb.z; bh_[3] = (_Float16)fb.w;
        *(half4*)&As[0][row][col] = ah;
        *(half4*)&Bs[0][row][col] = bh_;
      } else {
        split4(fa, ah, al);
        split4(fb, bh_, bl_);
        *(half4*)&As[0][row][col] = ah;
        *(half4*)&As[1][row][col] = al;
        *(half4*)&Bs[0][row][col] = bh_;
        *(half4*)&Bs[1][row][col] = bl_;
      }
    }
    __syncthreads();

    if (z == 2) {
      half8 a_h[4], b_h[4];
      #pragma unroll
      for (int t = 0; t < 4; t++) {
        a_h[t] = *(const half8*)&As[0][wm * 64 + t * 16 + l15][quad * 8];
        b_h[t] = *(const half8*)&Bs[0][wn * 64 + t * 16 + l15][quad * 8];
      }
      #pragma unroll
      for (int mt = 0; mt < 4; mt++)
        #pragma unroll
        for (int nt = 0; nt < 4; nt++)
          acc[mt][nt] = MFMA_F16(a_h[mt], b_h[nt], acc[mt][nt]);
    } else {
      half8 a_h[4], a_l[4], b_h[4], b_l[4];
      #pragma unroll
      for (int t = 0; t < 4; t++) {
        a_h[t] = *(const half8*)&As[0][wm * 64 + t * 16 + l15][quad * 8];
        a_l[t] = *(const half8*)&As[1][wm * 64 + t * 16 + l15][quad * 8];
        b_h[t] = *(const half8*)&Bs[0][wn * 64 + t * 16 + l15][quad * 8];
        b_l[t] = *(const half8*)&Bs[1][wn * 64 + t * 16 + l15][quad * 8];
      }
      #pragma unroll
      for (int mt = 0; mt < 4; mt++)
        #pragma unroll
        for (int nt = 0; nt < 4; nt++) {
          floatx4 t0 = MFMA_F16(a_h[mt], b_h[nt], acc[mt][nt]);
          t0 = MFMA_F16(a_h[mt], b_l[nt], t0);
          acc[mt][nt] = MFMA_F16(a_l[mt], b_h[nt], t0);
        }
    }
  }

  const float scale = (z == 0) ? QSCALE : 1.0f;
  #pragma unroll
  for (int mt = 0; mt < 4; mt++)
    #pragma unroll
    for (int nt = 0; nt < 4; nt++)
      #pragma unroll
      for (int r = 0; r < 4; r++) {
        int gm = bm * 128 + wm * 64 + mt * 16 + quad * 4 + r;   // (b,s)
        int gn = bn * 128 + wn * 64 + nt * 16 + l15;            // h*64+d
        int b = gm >> 11, s = gm & 2047;
        int h = gn >> 6, d = gn & 63;
        float val = acc[mt][nt][r] * scale;
        if (z == 2) {
          // permuted V^T: pos within 32-group: key 32c+16a+4q_+b_ -> 32c+8q_+4a+b_
          int pos = (s & ~31) | (((s >> 2) & 3) << 3) | (((s >> 4) & 1) << 2) | (s & 3);
          vhT[((size_t)(b * NH + h) * HD + d) * SEQ + pos] = (_Float16)val;
        } else {
          size_t idx = ((size_t)(b * NH + h) * SEQ + s) * HD + d;
          _Float16 hi = (_Float16)val;
          _Float16 lo = (_Float16)(val - (float)hi);
          if (z == 0) { qh_hi[idx] = hi; qh_lo[idx] = lo; }
          else        { kh_hi[idx] = hi; kh_lo[idx] = lo; }
        }
      }
}

// ---------------- flash attention v4 ----------------
// block = 4 waves, 32 q per wave (two 16-q groups), 128 q per block.
// grid (bh=32, qb=16) = 512 blocks = 2/CU, 8 waves/CU.
// K/V staged in LDS (coalesced global loads, prefetch pipeline);
// S^T = K·Q^T; P register-resident via key permutation; O^T = V~·P~.
__global__ __launch_bounds__(256, 2) void flash_kernel(
    const _Float16* __restrict__ qh_hi, const _Float16* __restrict__ qh_lo,
    const _Float16* __restrict__ kh_hi, const _Float16* __restrict__ kh_lo,
    const _Float16* __restrict__ vhT, float* __restrict__ out)
{
  __shared__ __align__(16) _Float16 Kh[64][72];
  __shared__ __align__(16) _Float16 Kl[64][72];
  __shared__ __align__(16) _Float16 Vt[64][72];   // [d][permuted key]

  const int bh = blockIdx.x;          // 0..31
  const int qb = blockIdx.y;          // 0..15 (128 q per block)
  const int tid = threadIdx.x;
  const int wq = tid >> 6;
  const int lane = tid & 63;
  const int l15 = lane & 15;
  const int quad = lane >> 4;

  const size_t bh_off = (size_t)bh * SEQ * HD;
  const _Float16* __restrict__ kh_p = kh_hi + bh_off;
  const _Float16* __restrict__ kl_p = kh_lo + bh_off;
  const _Float16* __restrict__ vt_p = vhT + (size_t)bh * HD * SEQ;
  const int qrow0 = qb * 128 + wq * 32;

  // Q as B-operand fragments: lane holds n=q=l15, k=d=kc*32+quad*8+j
  half8 bqh[2][2], bql[2][2];         // [g][kc]
  #pragma unroll
  for (int g = 0; g < 2; g++) {
    const _Float16* qp_h = qh_hi + bh_off + (size_t)(qrow0 + g * 16 + l15) * HD;
    const _Float16* qp_l = qh_lo + bh_off + (size_t)(qrow0 + g * 16 + l15) * HD;
    #pragma unroll
    for (int kc = 0; kc < 2; kc++) {
      bqh[g][kc] = *(const half8*)(qp_h + kc * 32 + quad * 8);
      bql[g][kc] = *(const half8*)(qp_l + kc * 32 + quad * 8);
    }
  }

  // staging: 512 half8-chunks per 64x64 array; 2 chunks/thread each
  const int c0 = tid, c1 = tid + 256;
  const int row0 = c0 >> 3, off0 = (c0 & 7) * 8;
  const int row1 = c1 >> 3, off1 = (c1 & 7) * 8;

  half8 pk0h, pk1h, pk0l, pk1l, pv0, pv1;   // prefetch registers
  {
    pk0h = *(const half8*)(kh_p + (size_t)row0 * HD + off0);
    pk1h = *(const half8*)(kh_p + (size_t)row1 * HD + off1);
    pk0l = *(const half8*)(kl_p + (size_t)row0 * HD + off0);
    pk1l = *(const half8*)(kl_p + (size_t)row1 * HD + off1);
    pv0  = *(const half8*)(vt_p + (size_t)row0 * SEQ + off0);
    pv1  = *(const half8*)(vt_p + (size_t)row1 * SEQ + off1);
  }

  float m_[2] = {-3.0e38f, -3.0e38f};
  float l_[2] = {0.f, 0.f};
  floatx4 Oacc[2][4];
  #pragma unroll
  for (int g = 0; g < 2; g++)
    #pragma unroll
    for (int nd = 0; nd < 4; nd++) Oacc[g][nd] = (floatx4){0.f, 0.f, 0.f, 0.f};

  for (int kt = 0; kt < SEQ / 64; kt++) {
    __syncthreads();   // prior iteration's LDS reads complete
    *(half8*)&Kh[row0][off0] = pk0h;
    *(half8*)&Kh[row1][off1] = pk1h;
    *(half8*)&Kl[row0][off0] = pk0l;
    *(half8*)&Kl[row1][off1] = pk1l;
    *(half8*)&Vt[row0][off0] = pv0;
    *(half8*)&Vt[row1][off1] = pv1;
    if (kt + 1 < SEQ / 64) {          // prefetch next tile during compute
      const int nb = (kt + 1) * 64;
      pk0h = *(const half8*)(kh_p + (size_t)(nb + row0) * HD + off0);
      pk1h = *(const half8*)(kh_p + (size_t)(nb + row1) * HD + off1);
      pk0l = *(const half8*)(kl_p + (size_t)(nb + row0) * HD + off0);
      pk1l = *(const half8*)(kl_p + (size_t)(nb + row1) * HD + off1);
      pv0  = *(const half8*)(vt_p + (size_t)row0 * SEQ + nb + off0);
      pv1  = *(const half8*)(vt_p + (size_t)row1 * SEQ + nb + off1);
    }
    __syncthreads();   // staged tile visible

    // S^T = K·Q^T (3-term split fp16), both q-groups share K fragments
    floatx4 sacc[2][4];
    #pragma unroll
    for (int nt = 0; nt < 4; nt++) {
      half8 akh0 = *(const half8*)&Kh[nt * 16 + l15][quad * 8];
      half8 akh1 = *(const half8*)&Kh[nt * 16 + l15][32 + quad * 8];
      half8 akl0 = *(const half8*)&Kl[nt * 16 + l15][quad * 8];
      half8 akl1 = *(const half8*)&Kl[nt * 16 + l15][32 + quad * 8];
      #pragma unroll
      for (int g = 0; g < 2; g++) {
        floatx4 s4 = (floatx4){0.f, 0.f, 0.f, 0.f};
        s4 = MFMA_F16(akh0, bqh[g][0], s4);
        s4 = MFMA_F16(akh1, bqh[g][1], s4);
        s4 = MFMA_F16(akh0, bql[g][0], s4);
        s4 = MFMA_F16(akh1, bql[g][1], s4);
        s4 = MFMA_F16(akl0, bqh[g][0], s4);
        s4 = MFMA_F16(akl1, bqh[g][1], s4);
        sacc[g][nt] = s4;
      }
    }

    // V A-fragments (permuted layout -> contiguous b128), shared by both groups
    half8 av[4][2];
    #pragma unroll
    for (int nd = 0; nd < 4; nd++) {
      av[nd][0] = *(const half8*)&Vt[nd * 16 + l15][quad * 8];
      av[nd][1] = *(const half8*)&Vt[nd * 16 + l15][32 + quad * 8];
    }

    #pragma unroll
    for (int g = 0; g < 2; g++) {
      // online softmax over 64 keys: in-lane + 2 cross-quad shuffles
      float rmax = sacc[g][0][0];
      #pragma unroll
      for (int nt = 0; nt < 4; nt++)
        #pragma unroll
        for (int r = 0; r < 4; r++) rmax = fmaxf(rmax, sacc[g][nt][r]);
      rmax = fmaxf(rmax, __shfl_xor(rmax, 16, 64));
      rmax = fmaxf(rmax, __shfl_xor(rmax, 32, 64));
      const float mnew = fmaxf(m_[g], rmax);
      const float alpha = exp2f(m_[g] - mnew);
      m_[g] = mnew;

      float p[4][4];
      float rsum = 0.f;
      #pragma unroll
      for (int nt = 0; nt < 4; nt++)
        #pragma unroll
        for (int r = 0; r < 4; r++) {
          p[nt][r] = exp2f(sacc[g][nt][r] - mnew);
          rsum += p[nt][r];
        }
      rsum += __shfl_xor(rsum, 16, 64);
      rsum += __shfl_xor(rsum, 32, 64);
      l_[g] = l_[g] * alpha + rsum;

      // P pack for PV B-operand: bp8[kc][j] = p[2kc + (j>>2)][j&3] (in-lane)
      half8 bp8[2];
      #pragma unroll
      for (int kc = 0; kc < 2; kc++)
        #pragma unroll
        for (int j = 0; j < 8; j++)
          bp8[kc][j] = (_Float16)p[2 * kc + (j >> 2)][j & 3];

      #pragma unroll
      for (int nd = 0; nd < 4; nd++) {
        Oacc[g][nd][0] *= alpha; Oacc[g][nd][1] *= alpha;
        Oacc[g][nd][2] *= alpha; Oacc[g][nd][3] *= alpha;
        Oacc[g][nd] = MFMA_F16(av[nd][0], bp8[0], Oacc[g][nd]);
        Oacc[g][nd] = MFMA_F16(av[nd][1], bp8[1], Oacc[g][nd]);
      }
    }
  }

  // epilogue: O^T C-layout (row=d=nd*16+quad*4+r, col=q=l15) -> out fp32
  const int b = bh >> 4, h = bh & 15;
  #pragma unroll
  for (int g = 0; g < 2; g++) {
    const int s = qrow0 + g * 16 + l15;
    const float rinv = 1.0f / l_[g];
    float* obase = out + (size_t)(b * SEQ + s) * DM + h * HD;
    #pragma unroll
    for (int nd = 0; nd < 4; nd++) {
      float4 vv;
      vv.x = Oacc[g][nd][0] * rinv;
      vv.y = Oacc[g][nd][1] * rinv;
      vv.z = Oacc[g][nd][2] * rinv;
      vv.w = Oacc[g][nd][3] * rinv;
      *(float4*)(obase + nd * 16 + quad * 4) = vv;
    }
  }
}

extern "C" void kernel_launch(void* const* d_in, const int* in_sizes, int n_in,
                              void* d_out, int out_size, void* d_ws, size_t ws_size,
                              hipStream_t stream) {
  const float* q  = (const float*)d_in[0];
  const float* k  = (const float*)d_in[1];
  const float* v  = (const float*)d_in[2];
  const float* Wq = (const float*)d_in[3];
  const float* Wk = (const float*)d_in[4];
  const float* Wv = (const float*)d_in[5];
  float* out = (float*)d_out;

  const size_t SZ = (size_t)2 * NH * SEQ * HD;  // 8 MB per array
  _Float16* ws    = (_Float16*)d_ws;            // 40 MB total
  _Float16* qh_hi = ws + 0 * SZ;
  _Float16* qh_lo = ws + 1 * SZ;
  _Float16* kh_hi = ws + 2 * SZ;
  _Float16* kh_lo = ws + 3 * SZ;
  _Float16* vhT   = ws + 4 * SZ;                // permuted V^T

  proj_kernel<<<dim3(32, 8, 3), 256, 0, stream>>>(q, k, v, Wq, Wk, Wv,
                                                  qh_hi, qh_lo, kh_hi, kh_lo, vhT);
  flash_kernel<<<dim3(32, 16), 256, 0, stream>>>(qh_hi, qh_lo, kh_hi, kh_lo, vhT, out);
}

// Round 5
// 346.050 us; speedup vs baseline: 1.2681x; 1.1035x over previous
//
#include <hip/hip_runtime.h>

// MultiHeadAttention: B=2, S=2048, D=1024, H=16, HD=64, scores MULTIPLIED by 64.
// Pipeline: per z: convert (fp32 -> fp16 hi/lo) -> proj GEMM (BK=64, prefetch);
// then transpose_v (vh -> permuted V^T), flash split-K x2 (register-resident P),
// merge. Workspace 73 MiB with flash partials aliased over dead convert regions.

typedef _Float16 half4 __attribute__((ext_vector_type(4)));
typedef _Float16 half8 __attribute__((ext_vector_type(8)));
typedef float floatx4 __attribute__((ext_vector_type(4)));

#define MFMA_F16(a, b, c) __builtin_amdgcn_mfma_f32_16x16x32_f16((a), (b), (c), 0, 0, 0)

constexpr int SEQ = 2048;
constexpr int DM = 1024;
constexpr int NH = 16;
constexpr int HD = 64;
// 64 * log2(e): fold score scale + base-2 conversion into Q projection
constexpr float QSCALE = 92.33248261689366f;

__device__ inline void split4(const float4 f, half4& h, half4& l) {
  h[0] = (_Float16)f.x; l[0] = (_Float16)(f.x - (float)h[0]);
  h[1] = (_Float16)f.y; l[1] = (_Float16)(f.y - (float)h[1]);
  h[2] = (_Float16)f.z; l[2] = (_Float16)(f.z - (float)h[2]);
  h[3] = (_Float16)f.w; l[3] = (_Float16)(f.w - (float)h[3]);
}

// ---------------- convert: fp32 -> fp16 hi (+lo) ----------------
// blocks 0..4095: x (4M floats); blocks 4096..5119: W (1M floats)
__global__ __launch_bounds__(256) void convert_kernel(
    const float* __restrict__ x, const float* __restrict__ W,
    _Float16* __restrict__ xh, _Float16* __restrict__ xl,
    _Float16* __restrict__ Wh, _Float16* __restrict__ Wl, int do_lo)
{
  if (blockIdx.x < 4096) {
    int idx = blockIdx.x * 256 + threadIdx.x;
    float4 f = ((const float4*)x)[idx];
    half4 h, l; split4(f, h, l);
    *(half4*)(xh + (size_t)idx * 4) = h;
    if (do_lo) *(half4*)(xl + (size_t)idx * 4) = l;
  } else {
    int idx = (blockIdx.x - 4096) * 256 + threadIdx.x;
    float4 f = ((const float4*)W)[idx];
    half4 h, l; split4(f, h, l);
    *(half4*)(Wh + (size_t)idx * 4) = h;
    if (do_lo) *(half4*)(Wl + (size_t)idx * 4) = l;
  }
}

// ---------------- projection GEMM: y = A @ B^T (pre-converted fp16) ---------
// A [4096x1024] hi/lo halfs; B [1024x1024] hi/lo halfs (row = out-feature).
// three=1: 3-term split-fp16, writes yh+yl; three=0: single-term, yh only.
// Output layout [b,h,s,d]. 128x128 tile, BK=64, register prefetch.
__global__ __launch_bounds__(256, 1) void proj_kernel(
    const _Float16* __restrict__ Ahg, const _Float16* __restrict__ Alg,
    const _Float16* __restrict__ Bhg, const _Float16* __restrict__ Blg,
    _Float16* __restrict__ yh, _Float16* __restrict__ yl,
    float scale, int three)
{
  __shared__ __align__(16) _Float16 Ahs[128][72];
  __shared__ __align__(16) _Float16 Als[128][72];
  __shared__ __align__(16) _Float16 Bhs[128][72];
  __shared__ __align__(16) _Float16 Bls[128][72];

  const int tid = threadIdx.x;
  const int bm = blockIdx.x;          // 0..31
  const int bn = blockIdx.y;          // 0..7
  const int lane = tid & 63, l15 = lane & 15, quad = lane >> 4;
  const int w = tid >> 6, wm = w >> 1, wn = w & 1;

  int row_[4], col_[4];
  #pragma unroll
  for (int i = 0; i < 4; i++) { int c = i * 256 + tid; row_[i] = c >> 3; col_[i] = (c & 7) * 8; }

  half8 pah[4], pal[4], pbh[4], pbl[4];
  #pragma unroll
  for (int i = 0; i < 4; i++) {
    pah[i] = *(const half8*)(Ahg + (size_t)(bm * 128 + row_[i]) * DM + col_[i]);
    pbh[i] = *(const half8*)(Bhg + (size_t)(bn * 128 + row_[i]) * DM + col_[i]);
    if (three) {
      pal[i] = *(const half8*)(Alg + (size_t)(bm * 128 + row_[i]) * DM + col_[i]);
      pbl[i] = *(const half8*)(Blg + (size_t)(bn * 128 + row_[i]) * DM + col_[i]);
    }
  }

  floatx4 acc[4][4];
  #pragma unroll
  for (int mt = 0; mt < 4; mt++)
    #pragma unroll
    for (int nt = 0; nt < 4; nt++)
      acc[mt][nt] = (floatx4){0.f, 0.f, 0.f, 0.f};

  for (int kk = 0; kk < DM; kk += 64) {
    __syncthreads();
    #pragma unroll
    for (int i = 0; i < 4; i++) {
      *(half8*)&Ahs[row_[i]][col_[i]] = pah[i];
      *(half8*)&Bhs[row_[i]][col_[i]] = pbh[i];
      if (three) {
        *(half8*)&Als[row_[i]][col_[i]] = pal[i];
        *(half8*)&Bls[row_[i]][col_[i]] = pbl[i];
      }
    }
    if (kk + 64 < DM) {
      #pragma unroll
      for (int i = 0; i < 4; i++) {
        pah[i] = *(const half8*)(Ahg + (size_t)(bm * 128 + row_[i]) * DM + kk + 64 + col_[i]);
        pbh[i] = *(const half8*)(Bhg + (size_t)(bn * 128 + row_[i]) * DM + kk + 64 + col_[i]);
        if (three) {
          pal[i] = *(const half8*)(Alg + (size_t)(bm * 128 + row_[i]) * DM + kk + 64 + col_[i]);
          pbl[i] = *(const half8*)(Blg + (size_t)(bn * 128 + row_[i]) * DM + kk + 64 + col_[i]);
        }
      }
    }
    __syncthreads();

    #pragma unroll
    for (int kc = 0; kc < 2; kc++) {
      half8 ah[4], bh_[4], al[4], bl[4];
      #pragma unroll
      for (int t = 0; t < 4; t++) {
        ah[t]  = *(const half8*)&Ahs[wm * 64 + t * 16 + l15][kc * 32 + quad * 8];
        bh_[t] = *(const half8*)&Bhs[wn * 64 + t * 16 + l15][kc * 32 + quad * 8];
        if (three) {
          al[t] = *(const half8*)&Als[wm * 64 + t * 16 + l15][kc * 32 + quad * 8];
          bl[t] = *(const half8*)&Bls[wn * 64 + t * 16 + l15][kc * 32 + quad * 8];
        }
      }
      if (three) {
        #pragma unroll
        for (int mt = 0; mt < 4; mt++)
          #pragma unroll
          for (int nt = 0; nt < 4; nt++) {
            floatx4 t0 = MFMA_F16(ah[mt], bh_[nt], acc[mt][nt]);
            t0 = MFMA_F16(ah[mt], bl[nt], t0);
            acc[mt][nt] = MFMA_F16(al[mt], bh_[nt], t0);
          }
      } else {
        #pragma unroll
        for (int mt = 0; mt < 4; mt++)
          #pragma unroll
          for (int nt = 0; nt < 4; nt++)
            acc[mt][nt] = MFMA_F16(ah[mt], bh_[nt], acc[mt][nt]);
      }
    }
  }

  #pragma unroll
  for (int mt = 0; mt < 4; mt++)
    #pragma unroll
    for (int nt = 0; nt < 4; nt++)
      #pragma unroll
      for (int r = 0; r < 4; r++) {
        int gm = bm * 128 + wm * 64 + mt * 16 + quad * 4 + r;   // (b,s)
        int gn = bn * 128 + wn * 64 + nt * 16 + l15;            // h*64+d
        int b = gm >> 11, s = gm & 2047;
        int h = gn >> 6, d = gn & 63;
        size_t idx = ((size_t)(b * NH + h) * SEQ + s) * HD + d;
        float val = acc[mt][nt][r] * scale;
        _Float16 hi = (_Float16)val;
        yh[idx] = hi;
        if (three) yl[idx] = (_Float16)(val - (float)hi);
      }
}

// ---------------- vh [b,h,s,64] -> vhT [b,h,64,perm(s)] ----------------
// perm within 32-group: s = 32c+16a+4q+b -> pos = 32c+8q+4a+b, so flash PV
// A-fragments (key order 32kc+16(j>>2)+4quad+(j&3)) are contiguous b128 reads.
__global__ __launch_bounds__(256) void transpose_v(const _Float16* __restrict__ vh,
                                                   _Float16* __restrict__ vhT)
{
  __shared__ __align__(16) _Float16 T[128][72];
  const int bh = blockIdx.x, sc = blockIdx.y, tid = threadIdx.x;
  const _Float16* src = vh + ((size_t)bh * SEQ + sc * 128) * HD;
  #pragma unroll
  for (int i = 0; i < 4; i++) {
    int c = i * 256 + tid, row = c >> 3, off = (c & 7) * 8;
    *(half8*)&T[row][off] = *(const half8*)(src + (size_t)row * HD + off);
  }
  __syncthreads();
  _Float16* dst = vhT + (size_t)bh * HD * SEQ + sc * 128;
  #pragma unroll
  for (int i = 0; i < 4; i++) {
    int c = i * 256 + tid, hd = c >> 4, off = (c & 15) * 8;
    int base32 = off & ~31, qsel = (off >> 3) & 3;
    half8 vv;
    #pragma unroll
    for (int j = 0; j < 8; j++) {
      int s_local = base32 + 16 * (j >> 2) + 4 * qsel + (j & 3);
      vv[j] = T[s_local][hd];
    }
    *(half8*)(dst + (size_t)hd * SEQ + off) = vv;
  }
}

// ---------------- flash attention v5: split-K x2, register-resident P -------
// grid (bh=32, qb=16, split=2); block 4 waves, 32 q/wave. Each split covers 16
// key-tiles, writes unnormalized O^T partial + (m,l) to ws; merge combines.
__global__ __launch_bounds__(256, 4) void flash_kernel(
    const _Float16* __restrict__ qh_hi, const _Float16* __restrict__ qh_lo,
    const _Float16* __restrict__ kh_hi, const _Float16* __restrict__ kh_lo,
    const _Float16* __restrict__ vhT, float* __restrict__ Op, float2* __restrict__ ml)
{
  __shared__ __align__(16) _Float16 Kh[64][72];
  __shared__ __align__(16) _Float16 Kl[64][72];
  __shared__ __align__(16) _Float16 Vt[64][72];   // [d][permuted key]

  const int bh = blockIdx.x;          // 0..31
  const int qb = blockIdx.y;          // 0..15
  const int kh = blockIdx.z;          // 0..1
  const int tid = threadIdx.x;
  const int wq = tid >> 6;
  const int lane = tid & 63, l15 = lane & 15, quad = lane >> 4;

  const size_t bh_off = (size_t)bh * SEQ * HD;
  const _Float16* __restrict__ kh_p = kh_hi + bh_off;
  const _Float16* __restrict__ kl_p = kh_lo + bh_off;
  const _Float16* __restrict__ vt_p = vhT + (size_t)bh * HD * SEQ;
  const int qrow0 = qb * 128 + wq * 32;

  // Q as B-operand fragments: lane holds n=q=l15, k=d=kc*32+quad*8+j
  half8 bqh[2][2], bql[2][2];         // [g][kc]
  #pragma unroll
  for (int g = 0; g < 2; g++) {
    const _Float16* qp_h = qh_hi + bh_off + (size_t)(qrow0 + g * 16 + l15) * HD;
    const _Float16* qp_l = qh_lo + bh_off + (size_t)(qrow0 + g * 16 + l15) * HD;
    #pragma unroll
    for (int kc = 0; kc < 2; kc++) {
      bqh[g][kc] = *(const half8*)(qp_h + kc * 32 + quad * 8);
      bql[g][kc] = *(const half8*)(qp_l + kc * 32 + quad * 8);
    }
  }

  const int c0 = tid, c1 = tid + 256;
  const int row0 = c0 >> 3, off0 = (c0 & 7) * 8;
  const int row1 = c1 >> 3, off1 = (c1 & 7) * 8;

  float m_[2] = {-3.0e38f, -3.0e38f};
  float l_[2] = {0.f, 0.f};
  floatx4 Oacc[2][4];
  #pragma unroll
  for (int g = 0; g < 2; g++)
    #pragma unroll
    for (int nd = 0; nd < 4; nd++) Oacc[g][nd] = (floatx4){0.f, 0.f, 0.f, 0.f};

  const int kt0 = kh * 16;
  for (int kt = kt0; kt < kt0 + 16; kt++) {
    const int kbase = kt * 64;
    __syncthreads();
    {
      half8 t0 = *(const half8*)(kh_p + (size_t)(kbase + row0) * HD + off0);
      half8 t1 = *(const half8*)(kh_p + (size_t)(kbase + row1) * HD + off1);
      half8 t2 = *(const half8*)(kl_p + (size_t)(kbase + row0) * HD + off0);
      half8 t3 = *(const half8*)(kl_p + (size_t)(kbase + row1) * HD + off1);
      half8 t4 = *(const half8*)(vt_p + (size_t)row0 * SEQ + kbase + off0);
      half8 t5 = *(const half8*)(vt_p + (size_t)row1 * SEQ + kbase + off1);
      *(half8*)&Kh[row0][off0] = t0;
      *(half8*)&Kh[row1][off1] = t1;
      *(half8*)&Kl[row0][off0] = t2;
      *(half8*)&Kl[row1][off1] = t3;
      *(half8*)&Vt[row0][off0] = t4;
      *(half8*)&Vt[row1][off1] = t5;
    }
    __syncthreads();

    // S^T = K·Q^T (3-term split fp16), both q-groups share K fragments
    floatx4 sacc[2][4];
    #pragma unroll
    for (int nt = 0; nt < 4; nt++) {
      half8 akh0 = *(const half8*)&Kh[nt * 16 + l15][quad * 8];
      half8 akh1 = *(const half8*)&Kh[nt * 16 + l15][32 + quad * 8];
      half8 akl0 = *(const half8*)&Kl[nt * 16 + l15][quad * 8];
      half8 akl1 = *(const half8*)&Kl[nt * 16 + l15][32 + quad * 8];
      #pragma unroll
      for (int g = 0; g < 2; g++) {
        floatx4 s4 = (floatx4){0.f, 0.f, 0.f, 0.f};
        s4 = MFMA_F16(akh0, bqh[g][0], s4);
        s4 = MFMA_F16(akh1, bqh[g][1], s4);
        s4 = MFMA_F16(akh0, bql[g][0], s4);
        s4 = MFMA_F16(akh1, bql[g][1], s4);
        s4 = MFMA_F16(akl0, bqh[g][0], s4);
        s4 = MFMA_F16(akl1, bqh[g][1], s4);
        sacc[g][nt] = s4;
      }
    }

    #pragma unroll
    for (int g = 0; g < 2; g++) {
      // online softmax over 64 keys: in-lane + 2 cross-quad shuffles
      float rmax = sacc[g][0][0];
      #pragma unroll
      for (int nt = 0; nt < 4; nt++)
        #pragma unroll
        for (int r = 0; r < 4; r++) rmax = fmaxf(rmax, sacc[g][nt][r]);
      rmax = fmaxf(rmax, __shfl_xor(rmax, 16, 64));
      rmax = fmaxf(rmax, __shfl_xor(rmax, 32, 64));
      const float mnew = fmaxf(m_[g], rmax);
      const float alpha = exp2f(m_[g] - mnew);
      m_[g] = mnew;

      float rsum = 0.f;
      #pragma unroll
      for (int nt = 0; nt < 4; nt++)
        #pragma unroll
        for (int r = 0; r < 4; r++) {
          float p = exp2f(sacc[g][nt][r] - mnew);
          sacc[g][nt][r] = p;          // overwrite in place (frees registers)
          rsum += p;
        }
      rsum += __shfl_xor(rsum, 16, 64);
      rsum += __shfl_xor(rsum, 32, 64);
      l_[g] = l_[g] * alpha + rsum;

      // P pack for PV B-operand: bp8[kc][j] = p[2kc + (j>>2)][j&3] (in-lane)
      half8 bp8[2];
      #pragma unroll
      for (int kc = 0; kc < 2; kc++)
        #pragma unroll
        for (int j = 0; j < 8; j++)
          bp8[kc][j] = (_Float16)sacc[g][2 * kc + (j >> 2)][j & 3];

      #pragma unroll
      for (int nd = 0; nd < 4; nd++) {
        half8 av0 = *(const half8*)&Vt[nd * 16 + l15][quad * 8];
        half8 av1 = *(const half8*)&Vt[nd * 16 + l15][32 + quad * 8];
        Oacc[g][nd][0] *= alpha; Oacc[g][nd][1] *= alpha;
        Oacc[g][nd][2] *= alpha; Oacc[g][nd][3] *= alpha;
        Oacc[g][nd] = MFMA_F16(av0, bp8[0], Oacc[g][nd]);
        Oacc[g][nd] = MFMA_F16(av1, bp8[1], Oacc[g][nd]);
      }
    }
  }

  // epilogue: unnormalized O^T partial + (m,l)
  const size_t fqbase = (size_t)bh * SEQ + qrow0;
  #pragma unroll
  for (int g = 0; g < 2; g++) {
    const size_t fq = fqbase + g * 16 + l15;
    float* ob = Op + ((size_t)kh * 65536 + fq) * HD;
    #pragma unroll
    for (int nd = 0; nd < 4; nd++) {
      float4 vv;
      vv.x = Oacc[g][nd][0]; vv.y = Oacc[g][nd][1];
      vv.z = Oacc[g][nd][2]; vv.w = Oacc[g][nd][3];
      *(float4*)(ob + nd * 16 + quad * 4) = vv;
    }
    if (quad == 0) ml[kh * 65536 + fq] = make_float2(m_[g], l_[g]);
  }
}

// ---------------- merge the two split-K partials ----------------
__global__ __launch_bounds__(256) void merge_kernel(const float* __restrict__ Op,
                                                    const float2* __restrict__ ml,
                                                    float* __restrict__ out)
{
  const int tid = threadIdx.x;
  const int fq = blockIdx.x * 64 + (tid >> 2);
  const int dp = (tid & 3) * 16;
  float2 m0 = ml[fq], m1 = ml[65536 + fq];
  float M = fmaxf(m0.x, m1.x);
  float w0 = exp2f(m0.x - M), w1 = exp2f(m1.x - M);
  float rinv = 1.0f / (m0.y * w0 + m1.y * w1);
  int bh = fq >> 11, s = fq & 2047, b = bh >> 4, h = bh & 15;
  float* ob = out + ((size_t)(b * SEQ + s)) * DM + h * HD + dp;
  const float* p0 = Op + (size_t)fq * HD + dp;
  const float* p1 = p0 + (size_t)65536 * HD;
  #pragma unroll
  for (int j = 0; j < 4; j++) {
    float4 a = *(const float4*)(p0 + 4 * j);
    float4 c = *(const float4*)(p1 + 4 * j);
    float4 r;
    r.x = (a.x * w0 + c.x * w1) * rinv;
    r.y = (a.y * w0 + c.y * w1) * rinv;
    r.z = (a.z * w0 + c.z * w1) * rinv;
    r.w = (a.w * w0 + c.w * w1) * rinv;
    *(float4*)(ob + 4 * j) = r;
  }
}

extern "C" void kernel_launch(void* const* d_in, const int* in_sizes, int n_in,
                              void* d_out, int out_size, void* d_ws, size_t ws_size,
                              hipStream_t stream) {
  const float* q  = (const float*)d_in[0];
  const float* k  = (const float*)d_in[1];
  const float* v  = (const float*)d_in[2];
  const float* Wq = (const float*)d_in[3];
  const float* Wk = (const float*)d_in[4];
  const float* Wv = (const float*)d_in[5];
  float* out = (float*)d_out;

  // workspace layout (MiB offsets); flash partials alias dead convert regions.
  char* W = (char*)d_ws;
  const size_t MiB = 1ull << 20;
  _Float16* qh_hi = (_Float16*)(W + 0 * MiB);
  _Float16* qh_lo = (_Float16*)(W + 8 * MiB);
  _Float16* kh_hi = (_Float16*)(W + 16 * MiB);
  _Float16* kh_lo = (_Float16*)(W + 24 * MiB);
  _Float16* vhT   = (_Float16*)(W + 32 * MiB);
  _Float16* vh    = (_Float16*)(W + 40 * MiB);  // dead after transpose_v
  _Float16* xh    = (_Float16*)(W + 48 * MiB);  // dead after last proj
  _Float16* xl    = (_Float16*)(W + 56 * MiB);
  _Float16* Wh    = (_Float16*)(W + 64 * MiB);
  _Float16* Wl    = (_Float16*)(W + 66 * MiB);  // convert phase ends at 68 MiB
  float*    Op    = (float*)  (W + 40 * MiB);   // 2 x 16 MiB, aliases vh/xh/xl/Wh/Wl
  float2*   mlp   = (float2*) (W + 72 * MiB);   // 1 MiB; total 73 MiB

  // Q
  convert_kernel<<<5120, 256, 0, stream>>>(q, Wq, xh, xl, Wh, Wl, 1);
  proj_kernel<<<dim3(32, 8), 256, 0, stream>>>(xh, xl, Wh, Wl, qh_hi, qh_lo, QSCALE, 1);
  // K
  convert_kernel<<<5120, 256, 0, stream>>>(k, Wk, xh, xl, Wh, Wl, 1);
  proj_kernel<<<dim3(32, 8), 256, 0, stream>>>(xh, xl, Wh, Wl, kh_hi, kh_lo, 1.0f, 1);
  // V (single-term)
  convert_kernel<<<5120, 256, 0, stream>>>(v, Wv, xh, xl, Wh, Wl, 0);
  proj_kernel<<<dim3(32, 8), 256, 0, stream>>>(xh, xl, Wh, Wl, vh, vh, 1.0f, 0);

  transpose_v<<<dim3(32, 16), 256, 0, stream>>>(vh, vhT);
  flash_kernel<<<dim3(32, 16, 2), 256, 0, stream>>>(qh_hi, qh_lo, kh_hi, kh_lo, vhT, Op, mlp);
  merge_kernel<<<1024, 256, 0, stream>>>(Op, mlp, out);
}